// Round 2
// baseline (146.701 us; speedup 1.0000x reference)
//
#include <hip/hip_runtime.h>

#define NBATCH 32
#define SEQ    2048
#define NU     512

typedef __attribute__((ext_vector_type(8)))  short bf16x8;
typedef __attribute__((ext_vector_type(16))) float f32x16;

__device__ __forceinline__ short bf16_of(float f) {
  union { float f; unsigned u; } v; v.f = f;
  unsigned r = v.u + 0x7fffu + ((v.u >> 16) & 1u);   // RNE
  return (short)(r >> 16);
}

__device__ __forceinline__ float fast_tanh(float x) {
  float ax = __builtin_fabsf(x);
  float t  = __expf(-2.0f * ax);
  float r  = (1.0f - t) / (1.0f + t);
  return x < 0.0f ? -r : r;
}

// ---------- prep 1: pre-swizzled Wt: WtSw[col*512 + kt*32 + xs] = bf16(W[kt*32 + (xs ^ swz(col))][col])
// swz(col) (in shorts) = ((col>>1)&3)<<3. Linear copy of a col's 64B k-tile into LDS then
// reading at y = koff ^ swz(col) yields W[kt*32+koff..][col].
__global__ __launch_bounds__(256) void prep_w(const float* __restrict__ W,
                                              short* __restrict__ WtSw) {
  int idx = blockIdx.x * 256 + threadIdx.x;   // 0..262143
  int col = idx >> 9, rem = idx & 511;
  int kt = rem >> 5, xs = rem & 31;
  int k = kt * 32 + (xs ^ (((col >> 1) & 3) << 3));
  WtSw[idx] = bf16_of(W[(size_t)k * NU + col]);
}

// ---------- prep 2: first[b][u] = s_prev[b]@U + U_bias + W_bias ----------
__global__ __launch_bounds__(256) void prep_first(const float* __restrict__ sp,
                                                  const float* __restrict__ U,
                                                  const float* __restrict__ Ub,
                                                  const float* __restrict__ Wb,
                                                  float* __restrict__ first) {
  __shared__ float srow[NU];
  int b = blockIdx.x >> 1;
  int half = blockIdx.x & 1;
  int t = threadIdx.x;
  srow[t]       = sp[b * NU + t];
  srow[t + 256] = sp[b * NU + t + 256];
  __syncthreads();
  int col = half * 256 + t;
  float acc = Ub[col] + Wb[col];
  #pragma unroll 8
  for (int k = 0; k < NU; ++k) acc += srow[k] * U[(size_t)k * NU + col];
  first[b * NU + col] = acc;
}

// ---------- main: double-buffered k-tiled GEMM + fused tanh*V score partials ----------
// Block: 128 rows x 256 cols (half of N). 4 waves as 2x2 (wave tile 64 rows x 128 cols).
// 32x32x16 bf16 MFMA. A reg-staged fp32->bf16, B via global_load_lds from pre-swizzled WtSw.
__global__ __launch_bounds__(256) void attn_main(
    const float* __restrict__ h,      // (65536, 512) fp32
    const short* __restrict__ WtSw,   // pre-swizzled (512 cols x 512 k) bf16
    const float* __restrict__ first,  // (B, 512) incl. U_bias + W_bias
    const float* __restrict__ V,      // (512)
    float* __restrict__ s0,           // (65536) score partial, cols 0..255
    float* __restrict__ s1)           // (65536) score partial, cols 256..511
{
  __shared__ short Alds[2][128 * 32];   // 8 KB each: [row][32 k shorts], swizzled
  __shared__ short Blds[2][256 * 32];   // 16 KB each: [col][32 k shorts], swizzled
  __shared__ float scores_lds[128];

  const int tid  = threadIdx.x;
  const int lane = tid & 63;
  const int w    = tid >> 6;
  const int wr   = w >> 1, wc = w & 1;
  const int l31  = lane & 31, hi = lane >> 5;

  // XCD-aware remap: pair (panel, half 0/1) adjacent on the same XCD for h L2 reuse.
  const int bid = blockIdx.x;
  const int lb  = (bid & 7) * 128 + (bid >> 3);    // 1024 % 8 == 0 -> bijective
  const int panel = lb >> 1, half = lb & 1;
  const int rowbase = panel * 128;
  const int b = panel >> 4;                        // 16 panels per batch

  // ---- staging constants
  const int arow  = tid >> 1;                      // 0..127
  const int ahalf = tid & 1;                       // low/high 16 floats of the 32-k tile
  const float* hA = h + (size_t)(rowbase + arow) * NU + ahalf * 16;
  const int aswz  = ((arow >> 1) & 3) << 3;        // shorts
  const int aw0   = arow * 32 + ((ahalf * 16)     ^ aswz);
  const int aw1   = arow * 32 + ((ahalf * 16 + 8) ^ aswz);
  const short* bsrc0 = WtSw + (size_t)(half * 256 + (tid >> 2)) * NU + (tid & 3) * 8;

  // ---- compute-read constants
  int rowA[2], swA[2], colB[4], swB[4];
  #pragma unroll
  for (int rt = 0; rt < 2; ++rt) {
    rowA[rt] = wr * 64 + rt * 32 + l31;
    swA[rt]  = ((rowA[rt] >> 1) & 3) << 3;
  }
  #pragma unroll
  for (int ct = 0; ct < 4; ++ct) {
    colB[ct] = wc * 128 + ct * 32 + l31;
    swB[ct]  = ((colB[ct] >> 1) & 3) << 3;
  }

  f32x16 acc[2][4];
  #pragma unroll
  for (int rt = 0; rt < 2; ++rt)
    #pragma unroll
    for (int ct = 0; ct < 4; ++ct)
      #pragma unroll
      for (int r = 0; r < 16; ++r) acc[rt][ct][r] = 0.f;

  float4 r0, r1, r2, r3;

  // ---- prologue: stage kt=0 into buf 0
  #pragma unroll
  for (int j = 0; j < 4; ++j) {
    const short* src = bsrc0 + (size_t)j * 64 * NU;
    short* dst = &Blds[0][j * 2048 + (w << 9)];
    __builtin_amdgcn_global_load_lds((const __attribute__((address_space(1))) unsigned int*)src,
                                     (__attribute__((address_space(3))) unsigned int*)dst,
                                     16, 0, 0);
  }
  r0 = *reinterpret_cast<const float4*>(hA + 0);
  r1 = *reinterpret_cast<const float4*>(hA + 4);
  r2 = *reinterpret_cast<const float4*>(hA + 8);
  r3 = *reinterpret_cast<const float4*>(hA + 12);
  {
    bf16x8 v0, v1;
    v0[0]=bf16_of(r0.x); v0[1]=bf16_of(r0.y); v0[2]=bf16_of(r0.z); v0[3]=bf16_of(r0.w);
    v0[4]=bf16_of(r1.x); v0[5]=bf16_of(r1.y); v0[6]=bf16_of(r1.z); v0[7]=bf16_of(r1.w);
    v1[0]=bf16_of(r2.x); v1[1]=bf16_of(r2.y); v1[2]=bf16_of(r2.z); v1[3]=bf16_of(r2.w);
    v1[4]=bf16_of(r3.x); v1[5]=bf16_of(r3.y); v1[6]=bf16_of(r3.z); v1[7]=bf16_of(r3.w);
    *reinterpret_cast<bf16x8*>(&Alds[0][aw0]) = v0;
    *reinterpret_cast<bf16x8*>(&Alds[0][aw1]) = v1;
  }
  __syncthreads();

  // ---- main loop: 16 K-tiles of 32
  for (int kt = 0; kt < 16; ++kt) {
    const int cur = kt & 1;
    if (kt < 15) {
      // issue next tile's B (async -> LDS) and A (-> regs) early; latency hides under MFMA
      #pragma unroll
      for (int j = 0; j < 4; ++j) {
        const short* src = bsrc0 + (size_t)j * 64 * NU + (kt + 1) * 32;
        short* dst = &Blds[cur ^ 1][j * 2048 + (w << 9)];
        __builtin_amdgcn_global_load_lds((const __attribute__((address_space(1))) unsigned int*)src,
                                         (__attribute__((address_space(3))) unsigned int*)dst,
                                         16, 0, 0);
      }
      const float* hk = hA + (kt + 1) * 32;
      r0 = *reinterpret_cast<const float4*>(hk + 0);
      r1 = *reinterpret_cast<const float4*>(hk + 4);
      r2 = *reinterpret_cast<const float4*>(hk + 8);
      r3 = *reinterpret_cast<const float4*>(hk + 12);
    }

    // compute current buffer: 2 k-steps x (2 A + 4 B reads, 8 MFMA)
    #pragma unroll
    for (int ks = 0; ks < 2; ++ks) {
      bf16x8 af[2], bf[4];
      #pragma unroll
      for (int rt = 0; rt < 2; ++rt)
        af[rt] = *reinterpret_cast<const bf16x8*>(
            &Alds[cur][rowA[rt] * 32 + ((ks * 16 + hi * 8) ^ swA[rt])]);
      #pragma unroll
      for (int ct = 0; ct < 4; ++ct)
        bf[ct] = *reinterpret_cast<const bf16x8*>(
            &Blds[cur][colB[ct] * 32 + ((ks * 16 + hi * 8) ^ swB[ct])]);
      #pragma unroll
      for (int rt = 0; rt < 2; ++rt)
        #pragma unroll
        for (int ct = 0; ct < 4; ++ct)
          acc[rt][ct] = __builtin_amdgcn_mfma_f32_32x32x16_bf16(af[rt], bf[ct], acc[rt][ct], 0, 0, 0);
    }

    if (kt < 15) {
      bf16x8 v0, v1;
      v0[0]=bf16_of(r0.x); v0[1]=bf16_of(r0.y); v0[2]=bf16_of(r0.z); v0[3]=bf16_of(r0.w);
      v0[4]=bf16_of(r1.x); v0[5]=bf16_of(r1.y); v0[6]=bf16_of(r1.z); v0[7]=bf16_of(r1.w);
      v1[0]=bf16_of(r2.x); v1[1]=bf16_of(r2.y); v1[2]=bf16_of(r2.z); v1[3]=bf16_of(r2.w);
      v1[4]=bf16_of(r3.x); v1[5]=bf16_of(r3.y); v1[6]=bf16_of(r3.z); v1[7]=bf16_of(r3.w);
      *reinterpret_cast<bf16x8*>(&Alds[cur ^ 1][aw0]) = v0;
      *reinterpret_cast<bf16x8*>(&Alds[cur ^ 1][aw1]) = v1;
    }
    __syncthreads();
  }

  // ---- epilogue: tanh + V, reduce over cols -> per-row partial scores
  float fv[4], vv[4];
  #pragma unroll
  for (int ct = 0; ct < 4; ++ct) {
    int col = half * 256 + colB[ct];
    fv[ct] = first[b * NU + col];
    vv[ct] = V[col];
  }
  float part[2][16];
  #pragma unroll
  for (int rt = 0; rt < 2; ++rt) {
    #pragma unroll
    for (int r = 0; r < 16; ++r) {
      float p = 0.f;
      #pragma unroll
      for (int ct = 0; ct < 4; ++ct)
        p += vv[ct] * fast_tanh(fv[ct] + acc[rt][ct][r]);
      #pragma unroll
      for (int m = 1; m < 32; m <<= 1) p += __shfl_xor(p, m, 64);
      part[rt][r] = p;
    }
  }
  __syncthreads();
  if (wc == 0 && l31 == 0) {
    #pragma unroll
    for (int rt = 0; rt < 2; ++rt)
      #pragma unroll
      for (int r = 0; r < 16; ++r)
        scores_lds[wr * 64 + rt * 32 + (r & 3) + 8 * (r >> 2) + 4 * hi] = part[rt][r];
  }
  __syncthreads();
  if (wc == 1 && l31 == 0) {
    #pragma unroll
    for (int rt = 0; rt < 2; ++rt)
      #pragma unroll
      for (int r = 0; r < 16; ++r)
        scores_lds[wr * 64 + rt * 32 + (r & 3) + 8 * (r >> 2) + 4 * hi] += part[rt][r];
  }
  __syncthreads();
  if (tid < 128) {
    float* dst = half ? s1 : s0;
    dst[rowbase + tid] = scores_lds[tid];
  }
}

// ---------- softmax over S per batch (scores = s0 + s1) + context ----------
__global__ __launch_bounds__(256) void softmax_ctx(const float* __restrict__ sp,
                                                   const float* __restrict__ s1,
                                                   float* __restrict__ out) {
  const int b = blockIdx.x;
  const int t = threadIdx.x;
  float* wgt = out + NBATCH * NU + (size_t)b * SEQ;   // s0 lives here, overwritten below
  const float* s1b = s1 + (size_t)b * SEQ;
  __shared__ float red[4];

  float v[8];
  float mx = -1e30f;
  #pragma unroll
  for (int i = 0; i < 8; ++i) { v[i] = wgt[t + i * 256] + s1b[t + i * 256]; mx = fmaxf(mx, v[i]); }
  #pragma unroll
  for (int m = 1; m < 64; m <<= 1) mx = fmaxf(mx, __shfl_xor(mx, m, 64));
  if ((t & 63) == 0) red[t >> 6] = mx;
  __syncthreads();
  mx = fmaxf(fmaxf(red[0], red[1]), fmaxf(red[2], red[3]));
  __syncthreads();

  float se = 0.f;
  #pragma unroll
  for (int i = 0; i < 8; ++i) { v[i] = __expf(v[i] - mx); se += v[i]; }
  #pragma unroll
  for (int m = 1; m < 64; m <<= 1) se += __shfl_xor(se, m, 64);
  if ((t & 63) == 0) red[t >> 6] = se;
  __syncthreads();
  se = red[0] + red[1] + red[2] + red[3];
  __syncthreads();

  const float inv = 1.0f / se;
  float sw = 0.f;
  #pragma unroll
  for (int i = 0; i < 8; ++i) { float wi = v[i] * inv; wgt[t + i * 256] = wi; sw += wi; }
  #pragma unroll
  for (int m = 1; m < 64; m <<= 1) sw += __shfl_xor(sw, m, 64);
  if ((t & 63) == 0) red[t >> 6] = sw;
  __syncthreads();
  sw = red[0] + red[1] + red[2] + red[3];

  out[b * NU + t]       = sp[b * NU + t] * sw;
  out[b * NU + t + 256] = sp[b * NU + t + 256] * sw;
}

extern "C" void kernel_launch(void* const* d_in, const int* in_sizes, int n_in,
                              void* d_out, int out_size, void* d_ws, size_t ws_size,
                              hipStream_t stream) {
  (void)in_sizes; (void)n_in; (void)out_size; (void)ws_size;
  const float* s_prev = (const float*)d_in[0];
  const float* h      = (const float*)d_in[1];
  const float* Wk     = (const float*)d_in[2];
  const float* Wb     = (const float*)d_in[3];
  const float* Uk     = (const float*)d_in[4];
  const float* Ub     = (const float*)d_in[5];
  const float* Vk     = (const float*)d_in[6];
  // d_in[7] = V_bias: softmax-shift-invariant, does not affect outputs.

  float* out   = (float*)d_out;
  float* first = (float*)d_ws;                               // 64 KB
  short* WtSw  = (short*)((char*)d_ws + 65536);              // 512 KB
  float* s1    = (float*)((char*)d_ws + 65536 + 524288);     // 256 KB
  float* s0    = out + NBATCH * NU;                          // scores half0 in weights slot

  prep_w     <<<1024, 256, 0, stream>>>(Wk, WtSw);
  prep_first <<<  64, 256, 0, stream>>>(s_prev, Uk, Ub, Wb, first);
  attn_main  <<<1024, 256, 0, stream>>>(h, WtSw, first, Vk, s0, s1);
  softmax_ctx<<<  32, 256, 0, stream>>>(s_prev, s1, out);
}

// Round 3
// 120.491 us; speedup vs baseline: 1.2175x; 1.2175x over previous
//
#include <hip/hip_runtime.h>

#define NBATCH 32
#define SEQ    2048
#define NU     512
#define ASTR   36   // shorts per LDS row (72 B): (18r+4h)%32 hits 16 distinct bank-groups -> 2-way (free)

typedef __attribute__((ext_vector_type(8)))  short bf16x8;
typedef __attribute__((ext_vector_type(16))) float f32x16;

__device__ __forceinline__ short bf16_of(float f) {
  union { float f; unsigned u; } v; v.f = f;
  unsigned r = v.u + 0x7fffu + ((v.u >> 16) & 1u);   // RNE
  return (short)(r >> 16);
}

__device__ __forceinline__ float fast_tanh(float x) {
  float ax = __builtin_fabsf(x);
  float t  = __expf(-2.0f * ax);
  float r  = (1.0f - t) / (1.0f + t);
  return x < 0.0f ? -r : r;
}

// ---------- prep 1: Wt[col][k] = bf16(W[k][col]) ----------
__global__ __launch_bounds__(256) void prep_w(const float* __restrict__ W,
                                              short* __restrict__ Wt) {
  int idx = blockIdx.x * 256 + threadIdx.x;   // 0..262143
  int u = idx >> 9, k = idx & 511;
  Wt[(size_t)u * NU + k] = bf16_of(W[(size_t)k * NU + u]);
}

// ---------- prep 2: first[b][u] = s_prev[b]@U + U_bias + W_bias ----------
__global__ __launch_bounds__(256) void prep_first(const float* __restrict__ sp,
                                                  const float* __restrict__ U,
                                                  const float* __restrict__ Ub,
                                                  const float* __restrict__ Wb,
                                                  float* __restrict__ first) {
  __shared__ float srow[NU];
  int b = blockIdx.x >> 1;
  int half = blockIdx.x & 1;
  int t = threadIdx.x;
  srow[t]       = sp[b * NU + t];
  srow[t + 256] = sp[b * NU + t + 256];
  __syncthreads();
  int col = half * 256 + t;
  float acc = Ub[col] + Wb[col];
  #pragma unroll 8
  for (int k = 0; k < NU; ++k) acc += srow[k] * U[(size_t)k * NU + col];
  first[b * NU + col] = acc;
}

// ---------- main: 128 rows x 128 cols per block (col-quarter), dbuf k-tiled ----------
// 4 waves as 2x2, wave tile 64x64 via 32x32x16 bf16 MFMA (acc = 64 regs/lane).
// Both A (h, fp32->bf16) and B (Wt) reg-staged into LDS; one barrier per K-tile.
__global__ __launch_bounds__(256, 3) void attn_main(
    const float* __restrict__ h,      // (65536, 512) fp32
    const short* __restrict__ Wt,     // (512 cols x 512 k) bf16
    const float* __restrict__ first,  // (B, 512) incl. U_bias + W_bias
    const float* __restrict__ V,      // (512)
    float* __restrict__ s0)           // (65536) score accumulator (pre-zeroed)
{
  __shared__ short Alds[2][128 * ASTR];   // 9216 B each
  __shared__ short Blds[2][128 * ASTR];   // 9216 B each
  __shared__ float scores_lds[128];

  const int tid  = threadIdx.x;
  const int lane = tid & 63;
  const int w    = tid >> 6;
  const int wr   = w >> 1, wc = w & 1;
  const int l31  = lane & 31, hi = lane >> 5;

  // XCD-aware remap: all 4 col-quarters of a row-panel on one XCD (h L2 reuse).
  const int bid = blockIdx.x;
  const int lb  = (bid & 7) * 256 + (bid >> 3);    // 2048 % 8 == 0 -> bijective
  const int panel = lb >> 2, q = lb & 3;
  const int rowbase = panel * 128;
  const int b = panel >> 4;                        // 16 panels per batch

  // staging addresses
  const int arow  = tid >> 1;                      // 0..127
  const int ahalf = tid & 1;                       // which 16-float half of the 32-k tile
  const float* hA = h + (size_t)(rowbase + arow) * NU + ahalf * 16;
  const int awr   = arow * ASTR + ahalf * 16;      // shorts
  const short* bsrc = Wt + (size_t)(q * 128 + arow) * NU + ahalf * 16;
  const int bwr   = awr;

  // compute-read bases (shorts)
  const int rA0 = (wr * 64 +  0 + l31) * ASTR + hi * 8;
  const int rA1 = (wr * 64 + 32 + l31) * ASTR + hi * 8;
  const int rB0 = (wc * 64 +  0 + l31) * ASTR + hi * 8;
  const int rB1 = (wc * 64 + 32 + l31) * ASTR + hi * 8;

  f32x16 acc[2][2];
  #pragma unroll
  for (int rt = 0; rt < 2; ++rt)
    #pragma unroll
    for (int ct = 0; ct < 2; ++ct)
      #pragma unroll
      for (int r = 0; r < 16; ++r) acc[rt][ct][r] = 0.f;

  float4 r0, r1, r2, r3;
  int4 q0, q1;

  // ---- prologue: stage k-tile 0 into buf 0
  r0 = *reinterpret_cast<const float4*>(hA + 0);
  r1 = *reinterpret_cast<const float4*>(hA + 4);
  r2 = *reinterpret_cast<const float4*>(hA + 8);
  r3 = *reinterpret_cast<const float4*>(hA + 12);
  q0 = *reinterpret_cast<const int4*>(bsrc + 0);
  q1 = *reinterpret_cast<const int4*>(bsrc + 8);
  {
    bf16x8 v0, v1;
    v0[0]=bf16_of(r0.x); v0[1]=bf16_of(r0.y); v0[2]=bf16_of(r0.z); v0[3]=bf16_of(r0.w);
    v0[4]=bf16_of(r1.x); v0[5]=bf16_of(r1.y); v0[6]=bf16_of(r1.z); v0[7]=bf16_of(r1.w);
    v1[0]=bf16_of(r2.x); v1[1]=bf16_of(r2.y); v1[2]=bf16_of(r2.z); v1[3]=bf16_of(r2.w);
    v1[4]=bf16_of(r3.x); v1[5]=bf16_of(r3.y); v1[6]=bf16_of(r3.z); v1[7]=bf16_of(r3.w);
    *reinterpret_cast<bf16x8*>(&Alds[0][awr])     = v0;
    *reinterpret_cast<bf16x8*>(&Alds[0][awr + 8]) = v1;
    *reinterpret_cast<int4*>(&Blds[0][bwr])       = q0;
    *reinterpret_cast<int4*>(&Blds[0][bwr + 8])   = q1;
  }
  __syncthreads();

  // ---- main loop: 16 K-tiles of 32
  for (int kt = 0; kt < 16; ++kt) {
    const int cur = kt & 1;
    if (kt < 15) {
      const float* hk = hA + (kt + 1) * 32;
      r0 = *reinterpret_cast<const float4*>(hk + 0);
      r1 = *reinterpret_cast<const float4*>(hk + 4);
      r2 = *reinterpret_cast<const float4*>(hk + 8);
      r3 = *reinterpret_cast<const float4*>(hk + 12);
      const short* bk = bsrc + (kt + 1) * 32;
      q0 = *reinterpret_cast<const int4*>(bk + 0);
      q1 = *reinterpret_cast<const int4*>(bk + 8);
    }

    // compute current buffer: 2 k-steps x (2 A + 2 B b128 reads, 4 MFMA)
    #pragma unroll
    for (int ks = 0; ks < 2; ++ks) {
      bf16x8 af[2], bf[2];
      af[0] = *reinterpret_cast<const bf16x8*>(&Alds[cur][rA0 + ks * 16]);
      af[1] = *reinterpret_cast<const bf16x8*>(&Alds[cur][rA1 + ks * 16]);
      bf[0] = *reinterpret_cast<const bf16x8*>(&Blds[cur][rB0 + ks * 16]);
      bf[1] = *reinterpret_cast<const bf16x8*>(&Blds[cur][rB1 + ks * 16]);
      #pragma unroll
      for (int rt = 0; rt < 2; ++rt)
        #pragma unroll
        for (int ct = 0; ct < 2; ++ct)
          acc[rt][ct] = __builtin_amdgcn_mfma_f32_32x32x16_bf16(af[rt], bf[ct], acc[rt][ct], 0, 0, 0);
    }

    if (kt < 15) {
      bf16x8 v0, v1;
      v0[0]=bf16_of(r0.x); v0[1]=bf16_of(r0.y); v0[2]=bf16_of(r0.z); v0[3]=bf16_of(r0.w);
      v0[4]=bf16_of(r1.x); v0[5]=bf16_of(r1.y); v0[6]=bf16_of(r1.z); v0[7]=bf16_of(r1.w);
      v1[0]=bf16_of(r2.x); v1[1]=bf16_of(r2.y); v1[2]=bf16_of(r2.z); v1[3]=bf16_of(r2.w);
      v1[4]=bf16_of(r3.x); v1[5]=bf16_of(r3.y); v1[6]=bf16_of(r3.z); v1[7]=bf16_of(r3.w);
      const int nxt = cur ^ 1;
      *reinterpret_cast<bf16x8*>(&Alds[nxt][awr])     = v0;
      *reinterpret_cast<bf16x8*>(&Alds[nxt][awr + 8]) = v1;
      *reinterpret_cast<int4*>(&Blds[nxt][bwr])       = q0;
      *reinterpret_cast<int4*>(&Blds[nxt][bwr + 8])   = q1;
    }
    __syncthreads();
  }

  // ---- epilogue: tanh + V, reduce over this block's 128 cols -> per-row partials
  float fv[2], vv[2];
  #pragma unroll
  for (int ct = 0; ct < 2; ++ct) {
    int col = q * 128 + wc * 64 + ct * 32 + l31;
    fv[ct] = first[b * NU + col];
    vv[ct] = V[col];
  }
  float part[2][16];
  #pragma unroll
  for (int rt = 0; rt < 2; ++rt) {
    #pragma unroll
    for (int r = 0; r < 16; ++r) {
      float p = 0.f;
      #pragma unroll
      for (int ct = 0; ct < 2; ++ct)
        p += vv[ct] * fast_tanh(fv[ct] + acc[rt][ct][r]);
      #pragma unroll
      for (int m = 1; m < 32; m <<= 1) p += __shfl_xor(p, m, 64);
      part[rt][r] = p;
    }
  }
  __syncthreads();
  if (wc == 0 && l31 == 0) {
    #pragma unroll
    for (int rt = 0; rt < 2; ++rt)
      #pragma unroll
      for (int r = 0; r < 16; ++r)
        scores_lds[wr * 64 + rt * 32 + (r & 3) + 8 * (r >> 2) + 4 * hi] = part[rt][r];
  }
  __syncthreads();
  if (wc == 1 && l31 == 0) {
    #pragma unroll
    for (int rt = 0; rt < 2; ++rt)
      #pragma unroll
      for (int r = 0; r < 16; ++r)
        scores_lds[wr * 64 + rt * 32 + (r & 3) + 8 * (r >> 2) + 4 * hi] += part[rt][r];
  }
  __syncthreads();
  if (tid < 128) atomicAdd(&s0[rowbase + tid], scores_lds[tid]);
}

// ---------- softmax over S per batch (in-place in d_out) + context ----------
__global__ __launch_bounds__(256) void softmax_ctx(const float* __restrict__ sp,
                                                   float* __restrict__ out) {
  const int b = blockIdx.x;
  const int t = threadIdx.x;
  float* wgt = out + NBATCH * NU + (size_t)b * SEQ;
  __shared__ float red[4];

  float v[8];
  float mx = -1e30f;
  #pragma unroll
  for (int i = 0; i < 8; ++i) { v[i] = wgt[t + i * 256]; mx = fmaxf(mx, v[i]); }
  #pragma unroll
  for (int m = 1; m < 64; m <<= 1) mx = fmaxf(mx, __shfl_xor(mx, m, 64));
  if ((t & 63) == 0) red[t >> 6] = mx;
  __syncthreads();
  mx = fmaxf(fmaxf(red[0], red[1]), fmaxf(red[2], red[3]));
  __syncthreads();

  float se = 0.f;
  #pragma unroll
  for (int i = 0; i < 8; ++i) { v[i] = __expf(v[i] - mx); se += v[i]; }
  #pragma unroll
  for (int m = 1; m < 64; m <<= 1) se += __shfl_xor(se, m, 64);
  if ((t & 63) == 0) red[t >> 6] = se;
  __syncthreads();
  se = red[0] + red[1] + red[2] + red[3];
  __syncthreads();

  const float inv = 1.0f / se;
  float sw = 0.f;
  #pragma unroll
  for (int i = 0; i < 8; ++i) { float wi = v[i] * inv; wgt[t + i * 256] = wi; sw += wi; }
  #pragma unroll
  for (int m = 1; m < 64; m <<= 1) sw += __shfl_xor(sw, m, 64);
  if ((t & 63) == 0) red[t >> 6] = sw;
  __syncthreads();
  sw = red[0] + red[1] + red[2] + red[3];

  out[b * NU + t]       = sp[b * NU + t] * sw;
  out[b * NU + t + 256] = sp[b * NU + t + 256] * sw;
}

extern "C" void kernel_launch(void* const* d_in, const int* in_sizes, int n_in,
                              void* d_out, int out_size, void* d_ws, size_t ws_size,
                              hipStream_t stream) {
  (void)in_sizes; (void)n_in; (void)out_size; (void)ws_size;
  const float* s_prev = (const float*)d_in[0];
  const float* h      = (const float*)d_in[1];
  const float* Wk     = (const float*)d_in[2];
  const float* Wb     = (const float*)d_in[3];
  const float* Uk     = (const float*)d_in[4];
  const float* Ub     = (const float*)d_in[5];
  const float* Vk     = (const float*)d_in[6];
  // d_in[7] = V_bias: softmax-shift-invariant, does not affect outputs.

  float* out   = (float*)d_out;
  float* first = (float*)d_ws;                    // 64 KB
  short* Wt    = (short*)((char*)d_ws + 65536);   // 512 KB
  float* s0    = out + NBATCH * NU;               // score accumulator in weights slot

  hipMemsetAsync(s0, 0, (size_t)NBATCH * SEQ * sizeof(float), stream);
  prep_w     <<<1024, 256, 0, stream>>>(Wk, Wt);
  prep_first <<<  64, 256, 0, stream>>>(s_prev, Uk, Ub, Wb, first);
  attn_main  <<<2048, 256, 0, stream>>>(h, Wt, first, Vk, s0);
  softmax_ctx<<<  32, 256, 0, stream>>>(s_prev, out);
}

// Round 4
// 113.528 us; speedup vs baseline: 1.2922x; 1.0613x over previous
//
#include <hip/hip_runtime.h>

#define NBATCH 32
#define SEQ    2048
#define NU     512
#define ASTR   36   // shorts per LDS row (72 B): read/write start-banks spread ~4 lanes/start

typedef __attribute__((ext_vector_type(8)))  short bf16x8;
typedef __attribute__((ext_vector_type(16))) float f32x16;

__device__ __forceinline__ short bf16_rne(float f) {
  union { float f; unsigned u; } v; v.f = f;
  unsigned r = v.u + 0x7fffu + ((v.u >> 16) & 1u);
  return (short)(r >> 16);
}

// pack bf16(lo), bf16(hi) (truncation) into one u32 via a single v_perm_b32
__device__ __forceinline__ unsigned pk2(float lo, float hi) {
  return __builtin_amdgcn_perm(__float_as_uint(hi), __float_as_uint(lo), 0x07060302u);
}

__device__ __forceinline__ float fast_tanh(float x) {
  float ax = __builtin_fabsf(x);
  float t  = __expf(-2.0f * ax);
  float r  = (1.0f - t) / (1.0f + t);
  return x < 0.0f ? -r : r;
}

// ---------- fused prep: blocks 0..1023 -> Wt[col][k]=bf16(W[k][col]); 1024..1087 -> first ----------
__global__ __launch_bounds__(256) void prep_all(const float* __restrict__ W,
                                                const float* __restrict__ sp,
                                                const float* __restrict__ U,
                                                const float* __restrict__ Ub,
                                                const float* __restrict__ Wb,
                                                short* __restrict__ Wt,
                                                float* __restrict__ first) {
  __shared__ float srow[NU];
  if (blockIdx.x < 1024) {
    int idx = blockIdx.x * 256 + threadIdx.x;
    int u = idx >> 9, k = idx & 511;
    Wt[(size_t)u * NU + k] = bf16_rne(W[(size_t)k * NU + u]);
  } else {
    int blk = blockIdx.x - 1024;           // 0..63
    int b = blk >> 1, half = blk & 1, t = threadIdx.x;
    srow[t]       = sp[b * NU + t];
    srow[t + 256] = sp[b * NU + t + 256];
    __syncthreads();
    int col = half * 256 + t;
    float acc = Ub[col] + Wb[col];
    #pragma unroll 8
    for (int k = 0; k < NU; ++k) acc += srow[k] * U[(size_t)k * NU + col];
    first[b * NU + col] = acc;
  }
}

// ---------- main: 128 rows x 128 cols per block, dbuf k-tiled, depth-2 h prefetch ----------
__global__ __launch_bounds__(256, 3) void attn_main(
    const float* __restrict__ h,      // (65536, 512) fp32
    const short* __restrict__ Wt,     // (512 cols x 512 k) bf16
    const float* __restrict__ first,  // (B, 512) incl. U_bias + W_bias
    const float* __restrict__ V,      // (512)
    float* __restrict__ s0)           // (65536) score accumulator (pre-zeroed)
{
  __shared__ short Alds[2][128 * ASTR];
  __shared__ short Blds[2][128 * ASTR];
  __shared__ float scores_lds[128];

  const int tid  = threadIdx.x;
  const int lane = tid & 63;
  const int w    = tid >> 6;
  const int wr   = w >> 1, wc = w & 1;
  const int l31  = lane & 31, hi = lane >> 5;

  // XCD-aware remap: 4 col-quarters of a row-panel adjacent on one XCD (h L2 reuse)
  const int bid = blockIdx.x;
  const int lb  = (bid & 7) * 256 + (bid >> 3);
  const int panel = lb >> 2, q = lb & 3;
  const int rowbase = panel * 128;
  const int b = panel >> 4;

  // staging addresses
  const int arow  = tid >> 1;
  const int ahalf = tid & 1;
  const float* hA = h + (size_t)(rowbase + arow) * NU + ahalf * 16;
  const int awr   = arow * ASTR + ahalf * 16;
  const short* bsrc = Wt + (size_t)(q * 128 + arow) * NU + ahalf * 16;

  // compute-read bases (shorts)
  const int rA0 = (wr * 64 +  0 + l31) * ASTR + hi * 8;
  const int rA1 = (wr * 64 + 32 + l31) * ASTR + hi * 8;
  const int rB0 = (wc * 64 +  0 + l31) * ASTR + hi * 8;
  const int rB1 = (wc * 64 + 32 + l31) * ASTR + hi * 8;

  f32x16 acc[2][2];
  #pragma unroll
  for (int rt = 0; rt < 2; ++rt)
    #pragma unroll
    for (int ct = 0; ct < 2; ++ct)
      #pragma unroll
      for (int r = 0; r < 16; ++r) acc[rt][ct][r] = 0.f;

  float4 ha0, ha1, ha2, ha3;   // h tile, even slot
  float4 hb0, hb1, hb2, hb3;   // h tile, odd slot
  int4   bq0, bq1;             // B tile in flight

  // pack-convert an h tile (16 floats) + B tile into LDS buffer `dst`
  #define CVT_WRITE(dst, H0, H1, H2, H3)                                   \
    {                                                                      \
      uint4 u0, u1;                                                        \
      u0.x = pk2(H0.x, H0.y); u0.y = pk2(H0.z, H0.w);                      \
      u0.z = pk2(H1.x, H1.y); u0.w = pk2(H1.z, H1.w);                      \
      u1.x = pk2(H2.x, H2.y); u1.y = pk2(H2.z, H2.w);                      \
      u1.z = pk2(H3.x, H3.y); u1.w = pk2(H3.z, H3.w);                      \
      *reinterpret_cast<uint4*>(&Alds[dst][awr])     = u0;                 \
      *reinterpret_cast<uint4*>(&Alds[dst][awr + 8]) = u1;                 \
      *reinterpret_cast<int4*>(&Blds[dst][awr])      = bq0;                \
      *reinterpret_cast<int4*>(&Blds[dst][awr + 8])  = bq1;                \
    }

  #define COMPUTE(cur)                                                     \
    _Pragma("unroll")                                                      \
    for (int ks = 0; ks < 2; ++ks) {                                       \
      bf16x8 af0, af1, bf0, bf1;                                           \
      af0 = *reinterpret_cast<const bf16x8*>(&Alds[cur][rA0 + ks * 16]);   \
      af1 = *reinterpret_cast<const bf16x8*>(&Alds[cur][rA1 + ks * 16]);   \
      bf0 = *reinterpret_cast<const bf16x8*>(&Blds[cur][rB0 + ks * 16]);   \
      bf1 = *reinterpret_cast<const bf16x8*>(&Blds[cur][rB1 + ks * 16]);   \
      acc[0][0] = __builtin_amdgcn_mfma_f32_32x32x16_bf16(af0, bf0, acc[0][0], 0, 0, 0); \
      acc[0][1] = __builtin_amdgcn_mfma_f32_32x32x16_bf16(af0, bf1, acc[0][1], 0, 0, 0); \
      acc[1][0] = __builtin_amdgcn_mfma_f32_32x32x16_bf16(af1, bf0, acc[1][0], 0, 0, 0); \
      acc[1][1] = __builtin_amdgcn_mfma_f32_32x32x16_bf16(af1, bf1, acc[1][1], 0, 0, 0); \
    }

  // ---- prologue: tile 0 staged, tile 1's h issued (depth-2 established)
  bq0 = *reinterpret_cast<const int4*>(bsrc);
  bq1 = *reinterpret_cast<const int4*>(bsrc + 8);
  ha0 = *reinterpret_cast<const float4*>(hA + 0);
  ha1 = *reinterpret_cast<const float4*>(hA + 4);
  ha2 = *reinterpret_cast<const float4*>(hA + 8);
  ha3 = *reinterpret_cast<const float4*>(hA + 12);
  CVT_WRITE(0, ha0, ha1, ha2, ha3);
  hb0 = *reinterpret_cast<const float4*>(hA + 32);
  hb1 = *reinterpret_cast<const float4*>(hA + 36);
  hb2 = *reinterpret_cast<const float4*>(hA + 40);
  hb3 = *reinterpret_cast<const float4*>(hA + 44);
  __syncthreads();

  // ---- main loop: kt = 0..13 in pairs (static reg slots, rule #20)
  for (int kt2 = 0; kt2 < 7; ++kt2) {
    const int kt = kt2 * 2;
    // even iter: compute LDS[0]; consume hb = h(kt+1); issue B(kt+1) then h(kt+2)->ha
    bq0 = *reinterpret_cast<const int4*>(bsrc + (kt + 1) * 32);
    bq1 = *reinterpret_cast<const int4*>(bsrc + (kt + 1) * 32 + 8);
    {
      const float* p = hA + (kt + 2) * 32;
      ha0 = *reinterpret_cast<const float4*>(p + 0);
      ha1 = *reinterpret_cast<const float4*>(p + 4);
      ha2 = *reinterpret_cast<const float4*>(p + 8);
      ha3 = *reinterpret_cast<const float4*>(p + 12);
    }
    COMPUTE(0);
    CVT_WRITE(1, hb0, hb1, hb2, hb3);
    __syncthreads();

    // odd iter: compute LDS[1]; consume ha = h(kt+2); issue B(kt+2) then h(kt+3)->hb
    bq0 = *reinterpret_cast<const int4*>(bsrc + (kt + 2) * 32);
    bq1 = *reinterpret_cast<const int4*>(bsrc + (kt + 2) * 32 + 8);
    {
      const float* p = hA + (kt + 3) * 32;
      hb0 = *reinterpret_cast<const float4*>(p + 0);
      hb1 = *reinterpret_cast<const float4*>(p + 4);
      hb2 = *reinterpret_cast<const float4*>(p + 8);
      hb3 = *reinterpret_cast<const float4*>(p + 12);
    }
    COMPUTE(1);
    CVT_WRITE(0, ha0, ha1, ha2, ha3);
    __syncthreads();
  }

  // kt = 14: compute LDS[0]; consume hb = h(15); issue B(15); no h prefetch
  bq0 = *reinterpret_cast<const int4*>(bsrc + 15 * 32);
  bq1 = *reinterpret_cast<const int4*>(bsrc + 15 * 32 + 8);
  COMPUTE(0);
  CVT_WRITE(1, hb0, hb1, hb2, hb3);
  __syncthreads();

  // kt = 15: compute LDS[1] only
  COMPUTE(1);

  #undef CVT_WRITE
  #undef COMPUTE

  // ---- epilogue: tanh + V, reduce over this block's 128 cols -> per-row partials
  float fv[2], vv[2];
  #pragma unroll
  for (int ct = 0; ct < 2; ++ct) {
    int col = q * 128 + wc * 64 + ct * 32 + l31;
    fv[ct] = first[b * NU + col];
    vv[ct] = V[col];
  }
  float part[2][16];
  #pragma unroll
  for (int rt = 0; rt < 2; ++rt) {
    #pragma unroll
    for (int r = 0; r < 16; ++r) {
      float p = 0.f;
      #pragma unroll
      for (int ct = 0; ct < 2; ++ct)
        p += vv[ct] * fast_tanh(fv[ct] + acc[rt][ct][r]);
      #pragma unroll
      for (int m = 1; m < 32; m <<= 1) p += __shfl_xor(p, m, 64);
      part[rt][r] = p;
    }
  }
  __syncthreads();
  if (wc == 0 && l31 == 0) {
    #pragma unroll
    for (int rt = 0; rt < 2; ++rt)
      #pragma unroll
      for (int r = 0; r < 16; ++r)
        scores_lds[wr * 64 + rt * 32 + (r & 3) + 8 * (r >> 2) + 4 * hi] = part[rt][r];
  }
  __syncthreads();
  if (wc == 1 && l31 == 0) {
    #pragma unroll
    for (int rt = 0; rt < 2; ++rt)
      #pragma unroll
      for (int r = 0; r < 16; ++r)
        scores_lds[wr * 64 + rt * 32 + (r & 3) + 8 * (r >> 2) + 4 * hi] += part[rt][r];
  }
  __syncthreads();
  if (tid < 128) atomicAdd(&s0[rowbase + tid], scores_lds[tid]);
}

// ---------- softmax over S per batch (in-place in d_out) + context ----------
__global__ __launch_bounds__(256) void softmax_ctx(const float* __restrict__ sp,
                                                   float* __restrict__ out) {
  const int b = blockIdx.x;
  const int t = threadIdx.x;
  float* wgt = out + NBATCH * NU + (size_t)b * SEQ;
  __shared__ float red[4];

  float v[8];
  float mx = -1e30f;
  #pragma unroll
  for (int i = 0; i < 8; ++i) { v[i] = wgt[t + i * 256]; mx = fmaxf(mx, v[i]); }
  #pragma unroll
  for (int m = 1; m < 64; m <<= 1) mx = fmaxf(mx, __shfl_xor(mx, m, 64));
  if ((t & 63) == 0) red[t >> 6] = mx;
  __syncthreads();
  mx = fmaxf(fmaxf(red[0], red[1]), fmaxf(red[2], red[3]));
  __syncthreads();

  float se = 0.f;
  #pragma unroll
  for (int i = 0; i < 8; ++i) { v[i] = __expf(v[i] - mx); se += v[i]; }
  #pragma unroll
  for (int m = 1; m < 64; m <<= 1) se += __shfl_xor(se, m, 64);
  if ((t & 63) == 0) red[t >> 6] = se;
  __syncthreads();
  se = red[0] + red[1] + red[2] + red[3];
  __syncthreads();

  const float inv = 1.0f / se;
  float sw = 0.f;
  #pragma unroll
  for (int i = 0; i < 8; ++i) { float wi = v[i] * inv; wgt[t + i * 256] = wi; sw += wi; }
  #pragma unroll
  for (int m = 1; m < 64; m <<= 1) sw += __shfl_xor(sw, m, 64);
  if ((t & 63) == 0) red[t >> 6] = sw;
  __syncthreads();
  sw = red[0] + red[1] + red[2] + red[3];

  out[b * NU + t]       = sp[b * NU + t] * sw;
  out[b * NU + t + 256] = sp[b * NU + t + 256] * sw;
}

extern "C" void kernel_launch(void* const* d_in, const int* in_sizes, int n_in,
                              void* d_out, int out_size, void* d_ws, size_t ws_size,
                              hipStream_t stream) {
  (void)in_sizes; (void)n_in; (void)out_size; (void)ws_size;
  const float* s_prev = (const float*)d_in[0];
  const float* h      = (const float*)d_in[1];
  const float* Wk     = (const float*)d_in[2];
  const float* Wb     = (const float*)d_in[3];
  const float* Uk     = (const float*)d_in[4];
  const float* Ub     = (const float*)d_in[5];
  const float* Vk     = (const float*)d_in[6];
  // d_in[7] = V_bias: softmax-shift-invariant, does not affect outputs.

  float* out   = (float*)d_out;
  float* first = (float*)d_ws;                    // 64 KB
  short* Wt    = (short*)((char*)d_ws + 65536);   // 512 KB
  float* s0    = out + NBATCH * NU;               // score accumulator in weights slot

  hipMemsetAsync(s0, 0, (size_t)NBATCH * SEQ * sizeof(float), stream);
  prep_all   <<<1088, 256, 0, stream>>>(Wk, s_prev, Uk, Ub, Wb, Wt, first);
  attn_main  <<<2048, 256, 0, stream>>>(h, Wt, first, Vk, s0);
  softmax_ctx<<<  32, 256, 0, stream>>>(s_prev, out);
}